// Round 1
// 156.726 us; speedup vs baseline: 1.2091x; 1.2091x over previous
//
#include <hip/hip_runtime.h>
#include <hip/hip_fp16.h>

#define EPSF 1e-6f

typedef _Float16 f16x8 __attribute__((ext_vector_type(8)));
typedef float f32x4 __attribute__((ext_vector_type(4)));

#define BK 32                  // K-tile (halves); LDS row = 64 B (4 x 16B segs)
#define SMEM_BYTES 49152       // max(2 x 18432 staging, 4 x 12288 fg scratch)
#define BUF_BYTES 18432        // 288 rows x 64 B

#define AS1 __attribute__((address_space(1)))
#define AS3 __attribute__((address_space(3)))

#define VM_WAIT(N) asm volatile("s_waitcnt vmcnt(" #N ")" ::: "memory")
#define LGKM0()    asm volatile("s_waitcnt lgkmcnt(0)" ::: "memory")

// ---------- wave sum -> scalar (SGPR) : pure DPP + readlane, no DS ops ----------
template <int CTRL>
__device__ __forceinline__ float dpp_add(float x) {
    int y = __builtin_amdgcn_update_dpp(0, __float_as_int(x), CTRL, 0xf, 0xf, true);
    return x + __int_as_float(y);
}

// After the 6 stages, lanes 48..63 hold the full 64-lane sum; readlane(63)
// returns it as a wave-uniform scalar (broadcast for free via SGPR).
__device__ __forceinline__ float wave_sum_bc(float x) {
    x = dpp_add<0xB1>(x);   // quad_perm xor1
    x = dpp_add<0x4E>(x);   // quad_perm xor2
    x = dpp_add<0x141>(x);  // row_half_mirror (xor4)
    x = dpp_add<0x140>(x);  // row_mirror (xor8) -> 16-group sums
    x = dpp_add<0x142>(x);  // row_bcast15: row1 += row0, row3 += row2
    x = dpp_add<0x143>(x);  // row_bcast31: rows 2,3 += (row0+row1)
    return __int_as_float(__builtin_amdgcn_readlane(__float_as_int(x), 63));
}

// ---------------- Phase 1: prepend cls, +EPS, L2-normalize, store fp16 packed ----------------
// A: [64 groups][80 rows][1024]  rows 0..36 = img 2g, 37..73 = img 2g+1, 74..79 = 0
// B: [128 caps][64 rows][1024]   row 0 = cls, 1..50 = caps, 51..63 = 0
__global__ __launch_bounds__(256) void norm_kernel(
        const float* __restrict__ img_cls, const float* __restrict__ imgs,
        const float* __restrict__ cap_cls, const float* __restrict__ caps,
        __half* __restrict__ Ah, __half* __restrict__ Bh) {
    __shared__ float red[4];
    const int row = blockIdx.x;
    const int tid = threadIdx.x;

    const float* src = nullptr;
    __half* dst;
    float eps_add = EPSF;
    if (row < 64 * 80) {
        const int g = row / 80, r = row % 80;
        dst = Ah + (size_t)row * 1024;
        int i = -1, rr = 0;
        if (r < 37)      { i = 2 * g;     rr = r; }
        else if (r < 74) { i = 2 * g + 1; rr = r - 37; }
        if (i >= 0) {
            if (rr == 0) { src = img_cls + (size_t)i * 1024; eps_add = 0.0f; }
            else         { src = imgs + ((size_t)i * 36 + (rr - 1)) * 1024; }
        }
    } else {
        const int row2 = row - 64 * 80;
        const int t = row2 >> 6, r = row2 & 63;
        dst = Bh + (size_t)row2 * 1024;
        if (r == 0)       { src = cap_cls + (size_t)t * 1024; eps_add = 0.0f; }
        else if (r <= 50) { src = caps + ((size_t)t * 50 + (r - 1)) * 1024; }
    }

    if (src == nullptr) {  // pad row: zeros (uniform across block)
        ushort4 z; z.x = z.y = z.z = z.w = 0;
        reinterpret_cast<ushort4*>(dst)[tid] = z;
        return;
    }

    float4 v = reinterpret_cast<const float4*>(src)[tid];
    v.x += eps_add; v.y += eps_add; v.z += eps_add; v.w += eps_add;
    float ss = v.x * v.x + v.y * v.y + v.z * v.z + v.w * v.w;
    #pragma unroll
    for (int m = 1; m <= 32; m <<= 1) ss += __shfl_xor(ss, m);
    if ((tid & 63) == 0) red[tid >> 6] = ss;
    __syncthreads();
    const float tot = red[0] + red[1] + red[2] + red[3];
    const float rn = 1.0f / sqrtf(tot);

    ushort4 o;
    o.x = __half_as_ushort(__float2half(v.x * rn));
    o.y = __half_as_ushort(__float2half(v.y * rn));
    o.z = __half_as_ushort(__float2half(v.z * rn));
    o.w = __half_as_ushort(__float2half(v.w * rn));
    reinterpret_cast<ushort4*>(dst)[tid] = o;
}

// ---------------- Phase 2: fused GEMM (BK=32 double-buffer) + Sinkhorn ----------------
// Block: 160 A rows (2 img-groups) x 128 B cols (2 caps), 4 waves.
// Wave (wm, wn) computes 80x64. Staging per K=32 tile: 18 hexadecets (16 rows
// x 64 B each); waves 0,1 take 5, waves 2,3 take 4.
// LDS linear 64B rows; XOR swizzle seg ^= (row&3) on global source + ds_read.
__device__ __forceinline__ void stage_oct(const __half* __restrict__ Ag,
                                          const __half* __restrict__ Bg,
                                          __half* buf, int kb, int o, size_t lofs) {
    const __half* src = (o < 10) ? (Ag + (size_t)o * 16384 + kb + lofs)
                                 : (Bg + (size_t)(o - 10) * 16384 + kb + lofs);
    __builtin_amdgcn_global_load_lds((const AS1 void*)src,
                                     (AS3 void*)(buf + o * 512), 16, 0, 0);
}

__device__ __forceinline__ void stage_tile(const __half* __restrict__ Ag,
                                           const __half* __restrict__ Bg,
                                           __half* buf, int kb, int wave,
                                           size_t lofs) {
    stage_oct(Ag, Bg, buf, kb, wave, lofs);
    stage_oct(Ag, Bg, buf, kb, wave + 4, lofs);
    stage_oct(Ag, Bg, buf, kb, wave + 8, lofs);
    stage_oct(Ag, Bg, buf, kb, wave + 12, lofs);
    if (wave < 2) stage_oct(Ag, Bg, buf, kb, wave + 16, lofs);
}

__device__ __forceinline__ void ds_loads32(const __half* buf, int wm, int wn,
                                           int fr, int q4, f16x8 af[5], f16x8 bf[4]) {
    const int soff = (q4 ^ (fr & 3)) * 8;   // swizzled seg, halves
    #pragma unroll
    for (int n = 0; n < 4; ++n) {
        const int R = 160 + wn * 64 + n * 16 + fr;
        bf[n] = *reinterpret_cast<const f16x8*>(buf + R * BK + soff);
    }
    #pragma unroll
    for (int m = 0; m < 5; ++m) {
        const int R = wm * 80 + m * 16 + fr;
        af[m] = *reinterpret_cast<const f16x8*>(buf + R * BK + soff);
    }
}

__device__ __forceinline__ void mfma_cluster(f32x4 acc[5][4], const f16x8 af[5],
                                             const f16x8 bf[4]) {
    __builtin_amdgcn_s_setprio(1);
    #pragma unroll
    for (int m = 0; m < 5; ++m)
        #pragma unroll
        for (int n = 0; n < 4; ++n)
            acc[m][n] = __builtin_amdgcn_mfma_f32_16x16x32_f16(af[m], bf[n], acc[m][n], 0, 0, 0);
    __builtin_amdgcn_s_setprio(0);
}

__global__ __launch_bounds__(256, 3) void fused_kernel(
        const __half* __restrict__ Ah, const __half* __restrict__ Bh,
        const int* __restrict__ img_lens, const int* __restrict__ cap_lens,
        float* __restrict__ out) {
    __shared__ __align__(16) char smem[SMEM_BYTES];   // 49,152 B -> 3 blocks/CU
    __half* lds0 = reinterpret_cast<__half*>(smem);
    __half* lds1 = reinterpret_cast<__half*>(smem + BUF_BYTES);

    // XCD-chunked mapping: 8 consecutive blocks share bx across 8 by slices.
    const int idx = blockIdx.x;            // 0..2047
    const int xcd = idx & 7;
    const int within = idx >> 3;           // 0..255
    const int bx = within >> 3;            // 0..31  (A double-group)
    const int by = xcd * 8 + (within & 7); // 0..63  (cap pair)

    const int tid = threadIdx.x;
    const int wave = tid >> 6;
    const int lane = tid & 63;
    const int wm = wave >> 1, wn = wave & 1;
    const int fr = lane & 15;
    const int q4 = lane >> 4;

    const __half* Ag = Ah + (size_t)bx * 160 * 1024;
    const __half* Bg = Bh + (size_t)by * 2 * 64 * 1024;

    // staging source offset: rsub = lane>>2 (row in hexadecet), global seg =
    // (lane&3) ^ (rsub&3)  (both-sides swizzle; LDS dest is linear)
    const int rsub = lane >> 2;
    const size_t lofs = (size_t)rsub * 1024 + (size_t)((((lane & 3) ^ (rsub & 3)) * 8));

    f32x4 acc[5][4];
    #pragma unroll
    for (int m = 0; m < 5; ++m)
        #pragma unroll
        for (int n = 0; n < 4; ++n) {
            f32x4 z = {0.0f, 0.0f, 0.0f, 0.0f};
            acc[m][n] = z;
        }

    // Prologue: tiles 0 and 1 in flight.
    stage_tile(Ag, Bg, lds0, 0, wave, lofs);
    stage_tile(Ag, Bg, lds1, BK, wave, lofs);
    if (wave < 2) { VM_WAIT(5); } else { VM_WAIT(4); }   // tile 0 landed
    __builtin_amdgcn_s_barrier();

    // Per tile kt (cur = buf[kt&1]):
    //   ds_loads(cur); lgkm0 (own reads retired); barrier (ALL waves' reads
    //   retired -> overwrite safe); stage(kt+2 -> cur); MFMA;
    //   vmcnt(own tile kt+2 count) (kt+1 landed, kt+2 in flight); barrier
    #pragma unroll 2
    for (int kt = 0; kt < 30; ++kt) {
        __half* cur = (kt & 1) ? lds1 : lds0;
        f16x8 af[5], bf[4];
        ds_loads32(cur, wm, wn, fr, q4, af, bf);
        LGKM0();                          // own reads of cur retired
        __builtin_amdgcn_s_barrier();     // => ALL waves' reads of cur retired
        stage_tile(Ag, Bg, cur, (kt + 2) * BK, wave, lofs);
        mfma_cluster(acc, af, bf);
        if (wave < 2) { VM_WAIT(5); } else { VM_WAIT(4); }   // kt+1 landed
        __builtin_amdgcn_s_barrier();
    }
    // ---- tile 30 (no staging; tile 31 in flight) ----
    {
        f16x8 af[5], bf[4];
        ds_loads32(lds0, wm, wn, fr, q4, af, bf);
        LGKM0();
        mfma_cluster(acc, af, bf);
        VM_WAIT(0);                       // tile 31 landed (own)
        __builtin_amdgcn_s_barrier();     // all waves' tile 31 visible
    }
    // ---- tile 31 ----
    {
        f16x8 af[5], bf[4];
        ds_loads32(lds1, wm, wn, fr, q4, af, bf);
        LGKM0();
        mfma_cluster(acc, af, bf);
    }

    __syncthreads();   // staging buffers become per-wave fg scratch

    // ---------------- Sinkhorn: wave-private fg region (48x64 XOR-swizzled), 2 passes ----------------
    // fg[row][col ^ (((row>>2)&3)<<4)] : writes 2-way (free), reads conflict-free.
    float* fg = reinterpret_cast<float*>(smem) + wave * (48 * 64);
    const int orow = q4 * 4;

    #pragma unroll
    for (int p = 0; p < 2; ++p) {
        if (p) {  // wave-local WAR: pass-0 fg reads must retire before rewrite
            LGKM0();
        }
        #pragma unroll
        for (int pm = 0; pm < 3; ++pm) {
            #pragma unroll
            for (int n = 0; n < 4; ++n) {
                const int colbase = (n * 16 + fr) ^ (q4 << 4);   // (row>>2)&3 == q4
                #pragma unroll
                for (int q = 0; q < 4; ++q)
                    fg[(pm * 16 + orow + q) * 64 + colbase] = acc[pm + 2 * p][n][q];
            }
        }

        const int i = 4 * bx + 2 * wm + p;
        const int t = 2 * by + wn;
        const int il = img_lens[i] + 1;        // 2..37
        const int cl = cap_lens[t] + 1;        // 2..51
        const bool vcol = lane < cl;
        const int rbase = p ? 5 : 0;           // pass-1 rows 37..73 = local 5..41

        #define FGR(r_) fg[((r_) + rbase) * 64 + \
                           (lane ^ (((((r_) + rbase) >> 2) & 3) << 4))]

        float P[37];
        float ts[4] = {0.f, 0.f, 0.f, 0.f};
        #pragma unroll
        for (int r = 0; r < 37; ++r) {
            if (r < il) {                       // wave-uniform branch
                const float f = FGR(r);
                const float pe = vcol ? __expf((f - 1.0f) * 10.0f) : 0.0f;
                P[r] = pe;
                ts[r & 3] += pe;
            } else {
                P[r] = 0.0f;
            }
        }
        float tot = (ts[0] + ts[1]) + (ts[2] + ts[3]);
        tot = wave_sum_bc(tot);
        const float s0 = __builtin_amdgcn_rcpf(tot + EPSF);
        #pragma unroll
        for (int r = 0; r < 37; ++r) P[r] *= s0;

        const float rmarg = 1.0f / (float)il;
        const float cmarg = 1.0f / (float)cl;
        for (int it = 0; it < 3; ++it) {
            #pragma unroll
            for (int r = 0; r < 37; ++r) {
                if (r < il) {
                    const float u = wave_sum_bc(P[r]);
                    P[r] *= rmarg * __builtin_amdgcn_rcpf(u + EPSF);
                }
            }
            float vs[4] = {EPSF, 0.f, 0.f, 0.f};
            #pragma unroll
            for (int r = 0; r < 37; ++r) vs[r & 3] += P[r];
            const float v = (vs[0] + vs[1]) + (vs[2] + vs[3]);
            const float cs = vcol ? cmarg * __builtin_amdgcn_rcpf(v) : 0.0f;
            #pragma unroll
            for (int r = 0; r < 37; ++r) P[r] *= cs;
        }

        float ls[4] = {0.f, 0.f, 0.f, 0.f};
        #pragma unroll
        for (int r = 0; r < 37; ++r) {
            if (r < il) ls[r & 3] += FGR(r) * P[r];   // re-read fg (saves 37 regs)
        }
        float local = (ls[0] + ls[1]) + (ls[2] + ls[3]);
        local = wave_sum_bc(local);
        if (lane == 0) out[i * 128 + t] = local;
        #undef FGR
    }
}

extern "C" void kernel_launch(void* const* d_in, const int* in_sizes, int n_in,
                              void* d_out, int out_size, void* d_ws, size_t ws_size,
                              hipStream_t stream) {
    const float* img_cls  = (const float*)d_in[0];
    const float* imgs     = (const float*)d_in[1];
    const float* cap_cls  = (const float*)d_in[2];
    const float* caps     = (const float*)d_in[3];
    const int*   img_lens = (const int*)d_in[4];
    const int*   cap_lens = (const int*)d_in[5];
    float* out = (float*)d_out;

    __half* Ah = (__half*)d_ws;                          // 64*80*1024 halves = 10.5 MB
    __half* Bh = Ah + (size_t)64 * 80 * 1024;            // 128*64*1024 halves = 16.8 MB

    norm_kernel<<<64 * 80 + 128 * 64, 256, 0, stream>>>(img_cls, imgs, cap_cls, caps, Ah, Bh);
    fused_kernel<<<2048, 256, 0, stream>>>(Ah, Bh, img_lens, cap_lens, out);
}